// Round 1
// baseline (97.948 us; speedup 1.0000x reference)
//
#include <hip/hip_runtime.h>

typedef __bf16 bf16x8 __attribute__((ext_vector_type(8)));
typedef float  f32x4  __attribute__((ext_vector_type(4)));

// Fused MLP: x=[h(64),b_in,b_out,J,-J] -> 64 relu -> 64 relu -> 5
// Computes Out^T = W^T * X^T per 16-row tile with mfma_f32_16x16x32_bf16.
// Rows live at lane&15 for both MFMA B-operand (n) and D (col) -> no
// cross-lane movement between layers. Feature->k-slot bijections:
//   layer1: f = 32*kk + 8*q + i          (kk=0..2, q=lane>>4, i=0..7; f>=69 zero, f==68 is constant-1 bias feature)
//   layer2/3: f = 16*(2*kk+(i>>2)) + 4*q + (i&3)   (matches D layout m=4q+r of the previous layer -> lane-local repack)
__global__ __launch_bounds__(256, 1)
void msg_mlp(const float* __restrict__ hbuf, const float* __restrict__ Jbuf,
             const float* __restrict__ binb, const float* __restrict__ boutb,
             const float* __restrict__ W1, const float* __restrict__ b1,
             const float* __restrict__ W2, const float* __restrict__ b2,
             const float* __restrict__ W3, const float* __restrict__ b3,
             float* __restrict__ out, int n_rows, int n_tiles)
{
    const int lane = threadIdx.x & 63;
    const int e = lane & 15;   // row-within-tile (B n-index and D col)
    const int q = lane >> 4;   // k-group
    const int wid = blockIdx.x * (blockDim.x >> 6) + (threadIdx.x >> 6);
    const int nw  = gridDim.x * (blockDim.x >> 6);

    // ---------------- weight fragments (register-resident, loaded once) ----------------
    bf16x8 a1[4][3];   // layer1: A = W1^T-ish, 4 m-tiles (64 outs) x 3 k-steps (K=96 padded)
#pragma unroll
    for (int mt = 0; mt < 4; ++mt)
#pragma unroll
      for (int kk = 0; kk < 3; ++kk)
#pragma unroll
        for (int i = 0; i < 8; ++i) {
          const int f = 32*kk + 8*q + i;
          const int o = 16*mt + e;
          float v = 0.0f;
          if (f < 68)       v = W1[f*64 + o];   // features 0..63=h, 64=b_in,65=b_out,66=J,67=-J
          else if (f == 68) v = b1[o];          // constant-1 feature carries bias
          a1[mt][kk][i] = (__bf16)v;
        }
    bf16x8 a2[4][2];   // layer2: K=64, 2 k-steps
#pragma unroll
    for (int mt = 0; mt < 4; ++mt)
#pragma unroll
      for (int kk = 0; kk < 2; ++kk)
#pragma unroll
        for (int i = 0; i < 8; ++i) {
          const int f = 16*(2*kk + (i>>2)) + 4*q + (i&3);
          a2[mt][kk][i] = (__bf16)W2[f*64 + 16*mt + e];
        }
    bf16x8 a3[2];      // layer3: 5 outs in one m-tile (rest zero)
#pragma unroll
    for (int kk = 0; kk < 2; ++kk)
#pragma unroll
      for (int i = 0; i < 8; ++i) {
        const int f = 16*(2*kk + (i>>2)) + 4*q + (i&3);
        a3[kk][i] = (e < 5) ? (__bf16)W3[f*5 + e] : (__bf16)0.0f;
      }
    float b2r[4][4];   // D layout: out = 16*mt + 4*q + r
#pragma unroll
    for (int mt = 0; mt < 4; ++mt)
#pragma unroll
      for (int r = 0; r < 4; ++r) b2r[mt][r] = b2[16*mt + 4*q + r];
    float b3r[4];
#pragma unroll
    for (int r = 0; r < 4; ++r) b3r[r] = (4*q + r < 5) ? b3[4*q + r] : 0.0f;

    // ---------------- per-tile input loads ----------------
    auto issue = [&](int t, f32x4& A, f32x4& Bv, f32x4& C, f32x4& D,
                     float& pin, float& pout, float& pj) {
      int re = t * 16 + e;
      if (re >= n_rows) re = n_rows - 1;           // clamp (garbage compute, store is guarded)
      const float* hr = hbuf + (size_t)re * 64 + 8*q;
      A  = *(const f32x4*)(hr);
      Bv = *(const f32x4*)(hr + 4);
      C  = *(const f32x4*)(hr + 32);
      D  = *(const f32x4*)(hr + 36);
      if (q == 0) { pin = binb[re]; pout = boutb[re]; pj = Jbuf[re]; }
      else        { pin = 0.0f;     pout = 0.0f;      pj = 0.0f; }
    };

    int t = wid;
    f32x4 A0, B0, C0, D0; float p0 = 0.f, q0 = 0.f, j0 = 0.f;
    if (t < n_tiles) issue(t, A0, B0, C0, D0, p0, q0, j0);

    for (; t < n_tiles; t += nw) {
      // prefetch next tile
      f32x4 A1, B1, C1, D1; float p1 = 0.f, q1 = 0.f, j1 = 0.f;
      const int tn = t + nw;
      if (tn < n_tiles) issue(tn, A1, B1, C1, D1, p1, q1, j1);

      // pack x -> bf16 B-fragments
      bf16x8 xb0, xb1, xb2;
#pragma unroll
      for (int i = 0; i < 4; ++i) {
        xb0[i]     = (__bf16)A0[i];
        xb0[i + 4] = (__bf16)B0[i];
        xb1[i]     = (__bf16)C0[i];
        xb1[i + 4] = (__bf16)D0[i];
      }
      xb2[0] = (__bf16)p0; xb2[1] = (__bf16)q0;
      xb2[2] = (__bf16)j0; xb2[3] = (__bf16)(-j0);
      xb2[4] = (q == 0) ? (__bf16)1.0f : (__bf16)0.0f;  // bias feature
      xb2[5] = (__bf16)0.0f; xb2[6] = (__bf16)0.0f; xb2[7] = (__bf16)0.0f;

      // ---- layer 1: [68->64] + relu (bias via k=68) ----
      f32x4 acc1[4];
#pragma unroll
      for (int mt = 0; mt < 4; ++mt) {
        acc1[mt] = (f32x4){0.f, 0.f, 0.f, 0.f};
        acc1[mt] = __builtin_amdgcn_mfma_f32_16x16x32_bf16(a1[mt][0], xb0, acc1[mt], 0, 0, 0);
        acc1[mt] = __builtin_amdgcn_mfma_f32_16x16x32_bf16(a1[mt][1], xb1, acc1[mt], 0, 0, 0);
        acc1[mt] = __builtin_amdgcn_mfma_f32_16x16x32_bf16(a1[mt][2], xb2, acc1[mt], 0, 0, 0);
      }
      bf16x8 y[2];   // lane-local repack: y[kk][i] = relu(acc1[2kk+(i>>2)][i&3])
#pragma unroll
      for (int kk = 0; kk < 2; ++kk)
#pragma unroll
        for (int i = 0; i < 8; ++i)
          y[kk][i] = (__bf16)fmaxf(acc1[2*kk + (i>>2)][i & 3], 0.0f);

      // ---- layer 2: [64->64] + relu ----
      f32x4 acc2[4];
#pragma unroll
      for (int mt = 0; mt < 4; ++mt) {
        acc2[mt] = (f32x4){b2r[mt][0], b2r[mt][1], b2r[mt][2], b2r[mt][3]};
        acc2[mt] = __builtin_amdgcn_mfma_f32_16x16x32_bf16(a2[mt][0], y[0], acc2[mt], 0, 0, 0);
        acc2[mt] = __builtin_amdgcn_mfma_f32_16x16x32_bf16(a2[mt][1], y[1], acc2[mt], 0, 0, 0);
      }
      bf16x8 z[2];
#pragma unroll
      for (int kk = 0; kk < 2; ++kk)
#pragma unroll
        for (int i = 0; i < 8; ++i)
          z[kk][i] = (__bf16)fmaxf(acc2[2*kk + (i>>2)][i & 3], 0.0f);

      // ---- layer 3: [64->5] ----
      f32x4 acc3 = (f32x4){b3r[0], b3r[1], b3r[2], b3r[3]};
      acc3 = __builtin_amdgcn_mfma_f32_16x16x32_bf16(a3[0], z[0], acc3, 0, 0, 0);
      acc3 = __builtin_amdgcn_mfma_f32_16x16x32_bf16(a3[1], z[1], acc3, 0, 0, 0);

      // ---- store: out feature m = 4q+r, row = 16t+e ----
      const int rowi = t * 16 + e;
      if (rowi < n_rows) {
        float* orow = out + (size_t)rowi * 5;
        if (q == 0) {
          orow[0] = acc3[0]; orow[1] = acc3[1];
          orow[2] = acc3[2]; orow[3] = acc3[3];
        } else if (q == 1) {
          orow[4] = acc3[0];
        }
      }

      // rotate prefetch
      A0 = A1; B0 = B1; C0 = C1; D0 = D1; p0 = p1; q0 = q1; j0 = j1;
    }
}

extern "C" void kernel_launch(void* const* d_in, const int* in_sizes, int n_in,
                              void* d_out, int out_size, void* d_ws, size_t ws_size,
                              hipStream_t stream) {
    const float* h     = (const float*)d_in[0];
    const float* J     = (const float*)d_in[1];
    const float* b_in  = (const float*)d_in[2];
    const float* b_out = (const float*)d_in[3];
    const float* W1    = (const float*)d_in[4];
    const float* b1    = (const float*)d_in[5];
    const float* W2    = (const float*)d_in[6];
    const float* b2    = (const float*)d_in[7];
    const float* W3    = (const float*)d_in[8];
    const float* b3    = (const float*)d_in[9];
    float* out = (float*)d_out;

    const int n_rows  = in_sizes[1];            // J has B*E elements
    const int n_tiles = (n_rows + 15) / 16;

    dim3 grid(512), block(256);                 // 2048 waves = exact residency at ~200 VGPR
    hipLaunchKernelGGL(msg_mlp, grid, block, 0, stream,
                       h, J, b_in, b_out, W1, b1, W2, b2, W3, b3,
                       out, n_rows, n_tiles);
}